// Round 3
// baseline (117.092 us; speedup 1.0000x reference)
//
#include <hip/hip_runtime.h>
#include <cmath>

#define WS   11
#define NX   160
#define NB   2
#define TH   16
#define TW   32
#define SH   (TH + 10)      // 26
#define SWP  44             // padded LDS row stride (floats), 16B-multiple
#define NF   5
#define DCHUNK 40

#define PLANE_I 8192000     // NB*NX*NX*NX (fits int; 5*PLANE < 2^31)

struct GaussW { float g[WS]; };

__constant__ const float C1v = 1.0e-4f;
__constant__ const float C2v = 9.0e-4f;

// Kernel 1: per (b,d) slice: stage x,y tile (cols [w0-6, w0+38), rows [h0-5,h0+21))
// in LDS, W-blur 4 outputs/thread via float4 sliding window building 5 fields on
// the fly, H-blur 2 rows/thread, write planar field volumes A[f][b][d][h][w].
// LDS = 2*26*44*4 + 5*26*32*4 = 25.8 KB -> 6 blocks/CU.
__global__ __launch_bounds__(256) void k_wh(const float* __restrict__ x,
                                            const float* __restrict__ y,
                                            float* __restrict__ A,
                                            GaussW gw) {
    __shared__ float sx[SH][SWP];
    __shared__ float sy[SH][SWP];
    __shared__ float mid[NF][SH][TW];

    const int tid = threadIdx.x;
    const int b  = blockIdx.z / NX;
    const int d  = blockIdx.z % NX;
    const int h0 = blockIdx.y * TH;
    const int w0 = blockIdx.x * TW;
    const int slice = (b * NX + d) * (NX * NX);

    // ---- stage x,y as float2 (global base w0-6 is even -> 8B aligned) ----
    for (int t = tid; t < SH * 22; t += 256) {
        const int r = t / 22, c2 = t % 22;
        const int gh = h0 - 5 + r;
        const int gwc = w0 - 6 + 2 * c2;
        float2 xv = make_float2(0.f, 0.f), yv = make_float2(0.f, 0.f);
        if ((unsigned)gh < (unsigned)NX) {
            const int o = slice + gh * NX + gwc;
            if (gwc >= 0 && gwc + 1 < NX) {
                xv = *(const float2*)(x + o);
                yv = *(const float2*)(y + o);
            } else {
                if ((unsigned)gwc < (unsigned)NX)       { xv.x = x[o];     yv.x = y[o]; }
                if ((unsigned)(gwc + 1) < (unsigned)NX) { xv.y = x[o + 1]; yv.y = y[o + 1]; }
            }
        }
        *(float2*)&sx[r][2 * c2] = xv;
        *(float2*)&sy[r][2 * c2] = yv;
    }
    __syncthreads();

    // ---- W-blur: 4 outputs/thread; window = local cols [c4, c4+16) ----
    // local col c <-> global w0-6+c; output j uses cols j+k+1 (k=0..10)
    if (tid < SH * 8) {
        const int r  = tid >> 3;
        const int c4 = (tid & 7) << 2;
        const float4* px = (const float4*)&sx[r][c4];
        const float4* py = (const float4*)&sy[r][c4];
        const float4 X0 = px[0], X1 = px[1], X2 = px[2], X3 = px[3];
        const float4 Y0 = py[0], Y1 = py[1], Y2 = py[2], Y3 = py[3];
        const float wx[16] = {X0.x,X0.y,X0.z,X0.w, X1.x,X1.y,X1.z,X1.w,
                              X2.x,X2.y,X2.z,X2.w, X3.x,X3.y,X3.z,X3.w};
        const float wy[16] = {Y0.x,Y0.y,Y0.z,Y0.w, Y1.x,Y1.y,Y1.z,Y1.w,
                              Y2.x,Y2.y,Y2.z,Y2.w, Y3.x,Y3.y,Y3.z,Y3.w};
        float a0[4] = {0,0,0,0}, a1[4] = {0,0,0,0}, a2[4] = {0,0,0,0},
              a3[4] = {0,0,0,0}, a4[4] = {0,0,0,0};
        #pragma unroll
        for (int k = 0; k < WS; ++k) {
            const float gk = gw.g[k];
            #pragma unroll
            for (int j = 0; j < 4; ++j) {
                const float xv = wx[j + k + 1];
                const float yv = wy[j + k + 1];
                const float t0 = gk * xv;
                const float t1 = gk * yv;
                a0[j] += t0;      a1[j] += t1;
                a2[j] += t0 * xv; a3[j] += t1 * yv; a4[j] += t0 * yv;
            }
        }
        *(float4*)&mid[0][r][c4] = make_float4(a0[0], a0[1], a0[2], a0[3]);
        *(float4*)&mid[1][r][c4] = make_float4(a1[0], a1[1], a1[2], a1[3]);
        *(float4*)&mid[2][r][c4] = make_float4(a2[0], a2[1], a2[2], a2[3]);
        *(float4*)&mid[3][r][c4] = make_float4(a3[0], a3[1], a3[2], a3[3]);
        *(float4*)&mid[4][r][c4] = make_float4(a4[0], a4[1], a4[2], a4[3]);
    }
    __syncthreads();

    // ---- H-blur: 2 consecutive rows/thread share a 12-row window ----
    {
        const int rg = tid >> 5;          // 0..7
        const int c  = tid & 31;
        const int r0 = rg * 2;
        float b0[NF] = {0,0,0,0,0}, b1[NF] = {0,0,0,0,0};
        #pragma unroll
        for (int k = 0; k < 12; ++k) {
            #pragma unroll
            for (int f = 0; f < NF; ++f) {
                const float v = mid[f][r0 + k][c];
                if (k <= 10) b0[f] += gw.g[k] * v;
                if (k >= 1)  b1[f] += gw.g[k - 1] * v;
            }
        }
        const int aofs = slice + (h0 + r0) * NX + w0 + c;
        #pragma unroll
        for (int f = 0; f < NF; ++f) {
            A[f * PLANE_I + aofs]      = b0[f];
            A[f * PLANE_I + aofs + NX] = b1[f];
        }
    }
}

// Kernel 2: D-blur with register sliding window + SSIM + block reduce.
__global__ __launch_bounds__(256) void k_d(const float* __restrict__ A,
                                           float* __restrict__ partial,
                                           GaussW gw) {
    const int tid = threadIdx.x;
    const long long gidx = (long long)blockIdx.x * 256 + tid;
    const int NCOL = NB * NX * NX;
    const int chunk = (int)(gidx / NCOL);
    const int col   = (int)(gidx % NCOL);
    const int b  = col / (NX * NX);
    const int hw = col % (NX * NX);
    const int base = b * (NX * NX * NX) + hw;
    const int d0 = chunk * DCHUNK;

    float win[NF][WS];
    #pragma unroll
    for (int i = 0; i < WS; ++i) {
        const int di = d0 - 5 + i;
        const bool ok = (di >= 0 && di < NX);
        const int o = base + (ok ? di : 0) * (NX * NX);
        #pragma unroll
        for (int f = 0; f < NF; ++f)
            win[f][i] = ok ? A[f * PLANE_I + o] : 0.f;
    }

    float acc = 0.f;
    for (int dd = 0; dd < DCHUNK; ++dd) {
        float m[NF];
        #pragma unroll
        for (int f = 0; f < NF; ++f) {
            float s = 0.f;
            #pragma unroll
            for (int i = 0; i < WS; ++i) s += gw.g[i] * win[f][i];
            m[f] = s;
        }
        const float mux = m[0], muy = m[1];
        const float mux2 = mux * mux, muy2 = muy * muy, muxy = mux * muy;
        const float sx_ = m[2] - mux2;
        const float sy_ = m[3] - muy2;
        const float sxy = m[4] - muxy;
        const float num = (2.f * muxy + C1v) * (2.f * sxy + C2v);
        const float den = (mux2 + muy2 + C1v) * (sx_ + sy_ + C2v);
        acc += num / den;

        const int dn = d0 + dd + 6;
        const bool ok = (dn < NX);
        const int o = base + (ok ? dn : 0) * (NX * NX);
        #pragma unroll
        for (int f = 0; f < NF; ++f) {
            #pragma unroll
            for (int i = 0; i < WS - 1; ++i) win[f][i] = win[f][i + 1];
            win[f][WS - 1] = ok ? A[f * PLANE_I + o] : 0.f;
        }
    }

    for (int off = 32; off > 0; off >>= 1) acc += __shfl_down(acc, off, 64);
    __shared__ float wsum[4];
    if ((tid & 63) == 0) wsum[tid >> 6] = acc;
    __syncthreads();
    if (tid == 0) partial[blockIdx.x] = wsum[0] + wsum[1] + wsum[2] + wsum[3];
}

__global__ __launch_bounds__(256) void k_red(const float* __restrict__ partial,
                                             int n, float* __restrict__ out) {
    double s = 0.0;
    for (int i = threadIdx.x; i < n; i += 256) s += (double)partial[i];
    __shared__ double sd[256];
    sd[threadIdx.x] = s;
    __syncthreads();
    for (int st = 128; st > 0; st >>= 1) {
        if (threadIdx.x < st) sd[threadIdx.x] += sd[threadIdx.x + st];
        __syncthreads();
    }
    if (threadIdx.x == 0)
        out[0] = (float)(sd[0] / (double)((long long)NB * NX * NX * NX));
}

extern "C" void kernel_launch(void* const* d_in, const int* in_sizes, int n_in,
                              void* d_out, int out_size, void* d_ws, size_t ws_size,
                              hipStream_t stream) {
    const float* x = (const float*)d_in[0];
    const float* y = (const float*)d_in[1];
    float* A = (float*)d_ws;
    float* partial = (float*)((char*)d_ws + (size_t)NF * PLANE_I * sizeof(float));

    GaussW gw;
    {
        float tmp[WS]; float s = 0.f;
        for (int i = 0; i < WS; ++i) {
            const double e = exp(-(double)((i - 5) * (i - 5)) / 4.5);
            tmp[i] = (float)e; s += tmp[i];
        }
        for (int i = 0; i < WS; ++i) gw.g[i] = tmp[i] / s;
    }

    dim3 g1(NX / TW, NX / TH, NB * NX);   // (5,10,320)
    k_wh<<<g1, 256, 0, stream>>>(x, y, A, gw);

    const int nblk2 = (NB * NX * NX * (NX / DCHUNK)) / 256;  // 800
    k_d<<<nblk2, 256, 0, stream>>>(A, partial, gw);

    k_red<<<1, 256, 0, stream>>>(partial, nblk2, (float*)d_out);
}